// Round 1
// baseline (2534.946 us; speedup 1.0000x reference)
//
#include <hip/hip_runtime.h>

// PathCon FFN — round 0: correct fp32 implementation.
// Structure: (1) atomic scatter-add aggregation, (2) node_rep finalize,
// (3) fused per-edge-tile FFN (GEMM1+LN1+GEMM2+relu+GEMM3+LN2) with LDS
// staging, never materializing h/u to HBM.

constexpr int NN = 50000;    // nodes
constexpr int NE = 400000;   // edges
constexpr int DI = 128;      // D_IN == D_OUT
constexpr int DN = 6;        // node feature dim
constexpr int DR = 134;      // node_rep width = DI + DN
constexpr int DC = 396;      // concat width = 2*DR + DI
constexpr float LN_EPS = 1e-5f;

constexpr int TM = 32;       // edges per block
constexpr int AP = 400;      // LDS pitch for edge_rep tile (pad 396->400, 16B aligned)
constexpr int HP = 132;      // LDS pitch for h tile (128->132, 16B aligned)
constexpr int UP = 260;      // LDS pitch for u tile (256->260, 16B aligned)

// ---------------------------------------------------------------- scatter ---
__global__ __launch_bounds__(256) void scatter_kernel(
    const float* __restrict__ edge_attr, const float* __restrict__ mask,
    const int* __restrict__ ei, float* __restrict__ node_out,
    float* __restrict__ den)
{
    int i = blockIdx.x * 256 + threadIdx.x;   // over NE*32 (one float4 chunk each)
    if (i >= NE * 32) return;
    int e = i >> 5, q = i & 31;
    float m = mask[e];
    if (m == 0.f) return;
    int col = ei[NE + e];
    if (q == 0) atomicAdd(&den[col], m);
    float4 v = reinterpret_cast<const float4*>(edge_attr)[(size_t)e * 32 + q];
    float* dst = node_out + (size_t)col * DR + q * 4;
    atomicAdd(dst + 0, v.x * m);
    atomicAdd(dst + 1, v.y * m);
    atomicAdd(dst + 2, v.z * m);
    atomicAdd(dst + 3, v.w * m);
}

// --------------------------------------------------------------- finalize ---
__global__ __launch_bounds__(256) void finalize_node_kernel(
    const float* __restrict__ x, const float* __restrict__ den,
    float* __restrict__ node_out)
{
    int i = blockIdx.x * 256 + threadIdx.x;
    if (i >= NN * DR) return;
    int n = i / DR;
    int d = i - n * DR;
    if (d < DI) {
        node_out[i] = node_out[i] / (den[n] + 1.0f);
    } else {
        node_out[i] = x[n * DN + (d - DI)];
    }
}

// -------------------------------------------------------------- fused FFN ---
__global__ __launch_bounds__(256) void ffn_kernel(
    const float* __restrict__ node_rep,   // [NN, DR]
    const float* __restrict__ edge_attr,  // [NE, DI]
    const int* __restrict__ ei,           // [2, NE]
    const float* __restrict__ W_edge, const float* __restrict__ b_edge,
    const float* __restrict__ W1, const float* __restrict__ b1,
    const float* __restrict__ W2, const float* __restrict__ b2,
    const float* __restrict__ g1, const float* __restrict__ be1,
    const float* __restrict__ g2, const float* __restrict__ be2,
    float* __restrict__ out)              // [NE, DI]
{
    __shared__ float A[TM * AP];          // edge_rep tile; aliased by Hs/Us later
    __shared__ float red[2][TM][8];
    __shared__ float mu_s[TM], rs_s[TM];

    const int t  = threadIdx.x;
    const int e0 = blockIdx.x * TM;

    // ---- stage edge_rep tile: [nr[row] | nr[col] | ea] ----
    for (int idx = t; idx < TM * DC; idx += 256) {
        int e = idx / DC;
        int k = idx - e * DC;
        int ge = e0 + e;
        float v;
        if (k < DR)          v = node_rep[(size_t)ei[ge] * DR + k];
        else if (k < 2 * DR) v = node_rep[(size_t)ei[NE + ge] * DR + (k - DR)];
        else                 v = edge_attr[(size_t)ge * DI + (k - 2 * DR)];
        A[e * AP + k] = v;
    }
    __syncthreads();

    const int et = t >> 5;   // 0..7  -> edges 4*et .. 4*et+3
    const int jt = t & 31;   // cols 4*jt .. 4*jt+3

    float* Hs = A;            // [TM][HP]   (aliases A[0 .. 4224))
    float* Us = A + TM * HP;  // [TM][UP]   (aliases A[4224 .. 12544))

    // ---- GEMM1: edge_rep @ W_edge ----
    float4 acc[4];
    #pragma unroll
    for (int i = 0; i < 4; ++i) acc[i] = make_float4(0.f, 0.f, 0.f, 0.f);
    for (int k0 = 0; k0 < DC; k0 += 4) {
        float4 w0 = *reinterpret_cast<const float4*>(&W_edge[(k0 + 0) * DI + 4 * jt]);
        float4 w1 = *reinterpret_cast<const float4*>(&W_edge[(k0 + 1) * DI + 4 * jt]);
        float4 w2 = *reinterpret_cast<const float4*>(&W_edge[(k0 + 2) * DI + 4 * jt]);
        float4 w3 = *reinterpret_cast<const float4*>(&W_edge[(k0 + 3) * DI + 4 * jt]);
        #pragma unroll
        for (int i = 0; i < 4; ++i) {
            float4 a4 = *reinterpret_cast<const float4*>(&A[(4 * et + i) * AP + k0]);
            acc[i].x += a4.x * w0.x + a4.y * w1.x + a4.z * w2.x + a4.w * w3.x;
            acc[i].y += a4.x * w0.y + a4.y * w1.y + a4.z * w2.y + a4.w * w3.y;
            acc[i].z += a4.x * w0.z + a4.y * w1.z + a4.z * w2.z + a4.w * w3.z;
            acc[i].w += a4.x * w0.w + a4.y * w1.w + a4.z * w2.w + a4.w * w3.w;
        }
    }
    __syncthreads();   // everyone done reading A before aliasing as Hs

    // ---- h_pre = edge_attr + GEMM1 + b_edge ----
    {
        float4 bev = *reinterpret_cast<const float4*>(&b_edge[4 * jt]);
        #pragma unroll
        for (int i = 0; i < 4; ++i) {
            int e = 4 * et + i;
            float4 res = *reinterpret_cast<const float4*>(&edge_attr[(size_t)(e0 + e) * DI + 4 * jt]);
            float4 h;
            h.x = res.x + acc[i].x + bev.x;
            h.y = res.y + acc[i].y + bev.y;
            h.z = res.z + acc[i].z + bev.z;
            h.w = res.w + acc[i].w + bev.w;
            *reinterpret_cast<float4*>(&Hs[e * HP + 4 * jt]) = h;
        }
    }
    __syncthreads();

    // ---- LN1 stats ----
    {
        int r = t >> 3, p = t & 7;
        float s = 0.f, ss = 0.f;
        #pragma unroll
        for (int j = 0; j < DI / 8; ++j) {
            float v = Hs[r * HP + p + 8 * j];
            s += v; ss += v * v;
        }
        red[0][r][p] = s; red[1][r][p] = ss;
    }
    __syncthreads();
    if (t < TM) {
        float s = 0.f, ss = 0.f;
        #pragma unroll
        for (int p = 0; p < 8; ++p) { s += red[0][t][p]; ss += red[1][t][p]; }
        float mu  = s * (1.f / DI);
        float var = ss * (1.f / DI) - mu * mu;
        mu_s[t] = mu;
        rs_s[t] = rsqrtf(var + LN_EPS);
    }
    __syncthreads();
    // ---- normalize h in place ----
    {
        float4 gv = *reinterpret_cast<const float4*>(&g1[4 * jt]);
        float4 bv = *reinterpret_cast<const float4*>(&be1[4 * jt]);
        #pragma unroll
        for (int i = 0; i < 4; ++i) {
            int e = 4 * et + i;
            float mu = mu_s[e], rs = rs_s[e];
            float4 h = *reinterpret_cast<float4*>(&Hs[e * HP + 4 * jt]);
            h.x = (h.x - mu) * rs * gv.x + bv.x;
            h.y = (h.y - mu) * rs * gv.y + bv.y;
            h.z = (h.z - mu) * rs * gv.z + bv.z;
            h.w = (h.w - mu) * rs * gv.w + bv.w;
            *reinterpret_cast<float4*>(&Hs[e * HP + 4 * jt]) = h;
        }
    }
    __syncthreads();

    // ---- GEMM2: u = relu(h @ W1 + b1) ----
    {
        const int et2 = t >> 6;   // 0..3 -> edges 8*et2 .. 8*et2+7
        const int jt2 = t & 63;   // cols 4*jt2 .. 4*jt2+3
        float4 acc2[8];
        #pragma unroll
        for (int i = 0; i < 8; ++i) acc2[i] = make_float4(0.f, 0.f, 0.f, 0.f);
        for (int k0 = 0; k0 < DI; k0 += 4) {
            float4 w0 = *reinterpret_cast<const float4*>(&W1[(k0 + 0) * 2 * DI + 4 * jt2]);
            float4 w1 = *reinterpret_cast<const float4*>(&W1[(k0 + 1) * 2 * DI + 4 * jt2]);
            float4 w2 = *reinterpret_cast<const float4*>(&W1[(k0 + 2) * 2 * DI + 4 * jt2]);
            float4 w3 = *reinterpret_cast<const float4*>(&W1[(k0 + 3) * 2 * DI + 4 * jt2]);
            #pragma unroll
            for (int i = 0; i < 8; ++i) {
                float4 h4 = *reinterpret_cast<const float4*>(&Hs[(8 * et2 + i) * HP + k0]);
                acc2[i].x += h4.x * w0.x + h4.y * w1.x + h4.z * w2.x + h4.w * w3.x;
                acc2[i].y += h4.x * w0.y + h4.y * w1.y + h4.z * w2.y + h4.w * w3.y;
                acc2[i].z += h4.x * w0.z + h4.y * w1.z + h4.z * w2.z + h4.w * w3.z;
                acc2[i].w += h4.x * w0.w + h4.y * w1.w + h4.z * w2.w + h4.w * w3.w;
            }
        }
        float4 b1v = *reinterpret_cast<const float4*>(&b1[4 * jt2]);
        #pragma unroll
        for (int i = 0; i < 8; ++i) {
            int e = 8 * et2 + i;
            float4 u;
            u.x = fmaxf(acc2[i].x + b1v.x, 0.f);
            u.y = fmaxf(acc2[i].y + b1v.y, 0.f);
            u.z = fmaxf(acc2[i].z + b1v.z, 0.f);
            u.w = fmaxf(acc2[i].w + b1v.w, 0.f);
            *reinterpret_cast<float4*>(&Us[e * UP + 4 * jt2]) = u;
        }
    }
    __syncthreads();

    // ---- GEMM3: y = h + u @ W2 + b2 ----
    float4 acc3[4];
    #pragma unroll
    for (int i = 0; i < 4; ++i) acc3[i] = make_float4(0.f, 0.f, 0.f, 0.f);
    for (int k0 = 0; k0 < 2 * DI; k0 += 4) {
        float4 w0 = *reinterpret_cast<const float4*>(&W2[(k0 + 0) * DI + 4 * jt]);
        float4 w1 = *reinterpret_cast<const float4*>(&W2[(k0 + 1) * DI + 4 * jt]);
        float4 w2 = *reinterpret_cast<const float4*>(&W2[(k0 + 2) * DI + 4 * jt]);
        float4 w3 = *reinterpret_cast<const float4*>(&W2[(k0 + 3) * DI + 4 * jt]);
        #pragma unroll
        for (int i = 0; i < 4; ++i) {
            float4 u4 = *reinterpret_cast<const float4*>(&Us[(4 * et + i) * UP + k0]);
            acc3[i].x += u4.x * w0.x + u4.y * w1.x + u4.z * w2.x + u4.w * w3.x;
            acc3[i].y += u4.x * w0.y + u4.y * w1.y + u4.z * w2.y + u4.w * w3.y;
            acc3[i].z += u4.x * w0.z + u4.y * w1.z + u4.z * w2.z + u4.w * w3.z;
            acc3[i].w += u4.x * w0.w + u4.y * w1.w + u4.z * w2.w + u4.w * w3.w;
        }
    }
    {
        float4 b2v = *reinterpret_cast<const float4*>(&b2[4 * jt]);
        #pragma unroll
        for (int i = 0; i < 4; ++i) {
            int e = 4 * et + i;
            float4 h = *reinterpret_cast<float4*>(&Hs[e * HP + 4 * jt]);
            h.x += acc3[i].x + b2v.x;
            h.y += acc3[i].y + b2v.y;
            h.z += acc3[i].z + b2v.z;
            h.w += acc3[i].w + b2v.w;
            *reinterpret_cast<float4*>(&Hs[e * HP + 4 * jt]) = h;   // same-thread RMW
        }
    }
    __syncthreads();

    // ---- LN2 stats ----
    {
        int r = t >> 3, p = t & 7;
        float s = 0.f, ss = 0.f;
        #pragma unroll
        for (int j = 0; j < DI / 8; ++j) {
            float v = Hs[r * HP + p + 8 * j];
            s += v; ss += v * v;
        }
        red[0][r][p] = s; red[1][r][p] = ss;
    }
    __syncthreads();
    if (t < TM) {
        float s = 0.f, ss = 0.f;
        #pragma unroll
        for (int p = 0; p < 8; ++p) { s += red[0][t][p]; ss += red[1][t][p]; }
        float mu  = s * (1.f / DI);
        float var = ss * (1.f / DI) - mu * mu;
        mu_s[t] = mu;
        rs_s[t] = rsqrtf(var + LN_EPS);
    }
    __syncthreads();

    // ---- final normalize + write ----
    {
        float4 gv = *reinterpret_cast<const float4*>(&g2[4 * jt]);
        float4 bv = *reinterpret_cast<const float4*>(&be2[4 * jt]);
        #pragma unroll
        for (int i = 0; i < 4; ++i) {
            int e = 4 * et + i;
            float mu = mu_s[e], rs = rs_s[e];
            float4 h = *reinterpret_cast<float4*>(&Hs[e * HP + 4 * jt]);
            float4 o;
            o.x = (h.x - mu) * rs * gv.x + bv.x;
            o.y = (h.y - mu) * rs * gv.y + bv.y;
            o.z = (h.z - mu) * rs * gv.z + bv.z;
            o.w = (h.w - mu) * rs * gv.w + bv.w;
            *reinterpret_cast<float4*>(&out[(size_t)(e0 + e) * DI + 4 * jt]) = o;
        }
    }
}

// ------------------------------------------------------------------ launch ---
extern "C" void kernel_launch(void* const* d_in, const int* in_sizes, int n_in,
                              void* d_out, int out_size, void* d_ws, size_t ws_size,
                              hipStream_t stream) {
    const float* x         = (const float*)d_in[0];
    const int*   ei        = (const int*)  d_in[1];
    const float* edge_attr = (const float*)d_in[2];
    const float* mask      = (const float*)d_in[3];
    // d_in[4] = num_nodes (compile-time constant NN)
    const float* W_edge    = (const float*)d_in[5];
    const float* b_edge    = (const float*)d_in[6];
    const float* W1        = (const float*)d_in[7];
    const float* b1        = (const float*)d_in[8];
    const float* W2        = (const float*)d_in[9];
    const float* b2        = (const float*)d_in[10];
    const float* g1        = (const float*)d_in[11];
    const float* be1       = (const float*)d_in[12];
    const float* g2        = (const float*)d_in[13];
    const float* be2       = (const float*)d_in[14];

    float* node_out  = (float*)d_out;                              // [NN, DR]
    float* out_edges = (float*)d_out + (size_t)NN * DR;            // [NE, DI]
    float* den       = (float*)d_ws;                               // [NN]

    hipMemsetAsync(node_out, 0, (size_t)NN * DR * sizeof(float), stream);
    hipMemsetAsync(den,      0, (size_t)NN * sizeof(float),      stream);

    scatter_kernel<<<(NE * 32) / 256, 256, 0, stream>>>(edge_attr, mask, ei, node_out, den);
    finalize_node_kernel<<<(NN * DR + 255) / 256, 256, 0, stream>>>(x, den, node_out);
    ffn_kernel<<<NE / TM, 256, 0, stream>>>(node_out, edge_attr, ei,
                                            W_edge, b_edge, W1, b1, W2, b2,
                                            g1, be1, g2, be2, out_edges);
}

// Round 2
// 1268.315 us; speedup vs baseline: 1.9987x; 1.9987x over previous
//
#include <hip/hip_runtime.h>

// PathCon FFN — round 1: MFMA bf16 restructure.
// edge_rep@W_edge = P[row] + Q[col] + ea@(Wc+I)  with P=nr@Wa+b_edge, Q=nr@Wb.
// FFN kernel: 1 wave per 16 edges, wave-private LDS, mfma_f32_16x16x32_bf16,
// LN via shfl_xor over 16-lane groups, h residual kept in registers.

constexpr int NN = 50000;
constexpr int NE = 400000;
constexpr int DI = 128;
constexpr int DN = 6;
constexpr int DR = 134;
constexpr float LN_EPS = 1e-5f;

using f4 = __attribute__((ext_vector_type(4))) float;
using s8 = __attribute__((ext_vector_type(8))) short;

__device__ __forceinline__ unsigned short f2bf(float f) {
    unsigned u = __float_as_uint(f);
    u += 0x7fff + ((u >> 16) & 1);   // RNE
    return (unsigned short)(u >> 16);
}

// ---------------------------------------------------------------- scatter ---
__global__ __launch_bounds__(256) void scatter_kernel(
    const float* __restrict__ edge_attr, const float* __restrict__ mask,
    const int* __restrict__ ei, float* __restrict__ node_out,
    float* __restrict__ den)
{
    int i = blockIdx.x * 256 + threadIdx.x;
    if (i >= NE * 32) return;
    int e = i >> 5, q = i & 31;
    float m = mask[e];
    if (m == 0.f) return;
    int col = ei[NE + e];
    if (q == 0) atomicAdd(&den[col], m);
    float4 v = reinterpret_cast<const float4*>(edge_attr)[(size_t)e * 32 + q];
    float* dst = node_out + (size_t)col * DR + q * 4;
    atomicAdd(dst + 0, v.x * m);
    atomicAdd(dst + 1, v.y * m);
    atomicAdd(dst + 2, v.z * m);
    atomicAdd(dst + 3, v.w * m);
}

// --------------------------------------------------------------- finalize ---
__global__ __launch_bounds__(256) void finalize_node_kernel(
    const float* __restrict__ x, const float* __restrict__ den,
    float* __restrict__ node_out)
{
    int i = blockIdx.x * 256 + threadIdx.x;
    if (i >= NN * DR) return;
    int n = i / DR;
    int d = i - n * DR;
    if (d < DI) node_out[i] = node_out[i] / (den[n] + 1.0f);
    else        node_out[i] = x[n * DN + (d - DI)];
}

// ----------------------------------------------------- bf16 weight prep ---
// WcT'[n][k] = W_edge[268+k][n] + (k==n)   (128x128)
// W1T [n][k] = W1[k][n]                    (256x128)
// W2T [n][k] = W2[k][n]                    (128x256)
__global__ __launch_bounds__(256) void prep_w_kernel(
    const float* __restrict__ W_edge, const float* __restrict__ W1,
    const float* __restrict__ W2,
    unsigned short* __restrict__ WcT, unsigned short* __restrict__ W1T,
    unsigned short* __restrict__ W2T)
{
    int idx = blockIdx.x * 256 + threadIdx.x;
    if (idx < 16384) {
        int n = idx >> 7, k = idx & 127;
        float v = W_edge[(268 + k) * 128 + n] + (k == n ? 1.f : 0.f);
        WcT[n * 128 + k] = f2bf(v);
    } else if (idx < 49152) {
        int j = idx - 16384;
        int n = j >> 7, k = j & 127;
        W1T[n * 128 + k] = f2bf(W1[k * 256 + n]);
    } else if (idx < 81920) {
        int j = idx - 49152;
        int n = j >> 8, k = j & 255;
        W2T[n * 256 + k] = f2bf(W2[k * 128 + n]);
    }
}

// ------------------------------------------------ P/Q node-level GEMMs ---
// P = node_rep @ Wa + b_edge ; Q = node_rep @ Wb   (K=134 padded to 136)
__global__ __launch_bounds__(256) void pq_kernel(
    const float* __restrict__ nr, const float* __restrict__ W_edge,
    const float* __restrict__ b_edge,
    float* __restrict__ P, float* __restrict__ Q)
{
    __shared__ float As[32 * 136];
    const int t = threadIdx.x;
    const int n0 = blockIdx.x * 32;

    for (int idx = t; idx < 32 * 136; idx += 256) {
        int n = idx / 136, k = idx - n * 136;
        float v = 0.f;
        if (n0 + n < NN && k < DR) v = nr[(size_t)(n0 + n) * DR + k];
        As[idx] = v;
    }
    __syncthreads();

    const int et = t >> 5, jt = t & 31;
    float4 accP[4], accQ[4];
    #pragma unroll
    for (int i = 0; i < 4; ++i) {
        accP[i] = make_float4(0.f, 0.f, 0.f, 0.f);
        accQ[i] = make_float4(0.f, 0.f, 0.f, 0.f);
    }
    for (int k0 = 0; k0 < 136; k0 += 4) {
        float4 wa[4], wb[4];
        #pragma unroll
        for (int d = 0; d < 4; ++d) {
            wa[d] = *reinterpret_cast<const float4*>(&W_edge[(size_t)(k0 + d) * 128 + 4 * jt]);
            wb[d] = *reinterpret_cast<const float4*>(&W_edge[(size_t)(134 + k0 + d) * 128 + 4 * jt]);
        }
        #pragma unroll
        for (int i = 0; i < 4; ++i) {
            float4 a4 = *reinterpret_cast<const float4*>(&As[(4 * et + i) * 136 + k0]);
            accP[i].x += a4.x * wa[0].x + a4.y * wa[1].x + a4.z * wa[2].x + a4.w * wa[3].x;
            accP[i].y += a4.x * wa[0].y + a4.y * wa[1].y + a4.z * wa[2].y + a4.w * wa[3].y;
            accP[i].z += a4.x * wa[0].z + a4.y * wa[1].z + a4.z * wa[2].z + a4.w * wa[3].z;
            accP[i].w += a4.x * wa[0].w + a4.y * wa[1].w + a4.z * wa[2].w + a4.w * wa[3].w;
            accQ[i].x += a4.x * wb[0].x + a4.y * wb[1].x + a4.z * wb[2].x + a4.w * wb[3].x;
            accQ[i].y += a4.x * wb[0].y + a4.y * wb[1].y + a4.z * wb[2].y + a4.w * wb[3].y;
            accQ[i].z += a4.x * wb[0].z + a4.y * wb[1].z + a4.z * wb[2].z + a4.w * wb[3].z;
            accQ[i].w += a4.x * wb[0].w + a4.y * wb[1].w + a4.z * wb[2].w + a4.w * wb[3].w;
        }
    }
    float4 bev = *reinterpret_cast<const float4*>(&b_edge[4 * jt]);
    #pragma unroll
    for (int i = 0; i < 4; ++i) {
        int n = n0 + 4 * et + i;
        if (n < NN) {
            float4 p = accP[i];
            p.x += bev.x; p.y += bev.y; p.z += bev.z; p.w += bev.w;
            *reinterpret_cast<float4*>(&P[(size_t)n * 128 + 4 * jt]) = p;
            *reinterpret_cast<float4*>(&Q[(size_t)n * 128 + 4 * jt]) = accQ[i];
        }
    }
}

// -------------------------------------------------------------- fused FFN ---
constexpr int LP = 264;   // per-row LDS pitch in bf16 units (528 B)

__global__ __launch_bounds__(256) void ffn_kernel(
    const float* __restrict__ edge_attr,  // [NE, 128]
    const int* __restrict__ ei,           // [2, NE]
    const float* __restrict__ P,          // [NN, 128]
    const float* __restrict__ Q,          // [NN, 128]
    const unsigned short* __restrict__ WcT,   // [128][128] bf16 (Wc+I)^T
    const unsigned short* __restrict__ W1T,   // [256][128] bf16
    const unsigned short* __restrict__ W2T,   // [128][256] bf16
    const float* __restrict__ b1, const float* __restrict__ b2,
    const float* __restrict__ g1, const float* __restrict__ be1,
    const float* __restrict__ g2, const float* __restrict__ be2,
    float* __restrict__ out)              // [NE, 128]
{
    __shared__ short lds_s[4 * 16 * LP];
    const int t    = threadIdx.x;
    const int w    = t >> 6;
    const int lane = t & 63;
    const int q    = lane >> 4;      // 0..3
    const int c    = lane & 15;      // 0..15
    const int e0w  = blockIdx.x * 64 + w * 16;
    short* Ls = lds_s + w * (16 * LP);

    // ---- stage ea tile as bf16 [16][128] (pitch LP) ----
    {
        int r  = lane >> 2;
        int cb = lane & 3;
        const float4* src = reinterpret_cast<const float4*>(edge_attr + (size_t)(e0w + r) * 128);
        #pragma unroll
        for (int i = 0; i < 8; ++i) {
            int chunk = cb + 4 * i;
            float4 v = src[chunk];
            ushort4 b;
            b.x = f2bf(v.x); b.y = f2bf(v.y); b.z = f2bf(v.z); b.w = f2bf(v.w);
            *reinterpret_cast<ushort4*>(Ls + r * LP + chunk * 4) = b;
        }
    }

    // ---- GEMM1: ea @ (Wc+I)  -> acc1[8] (16x128 D-tile per wave) ----
    f4 acc1[8];
    #pragma unroll
    for (int nt = 0; nt < 8; ++nt) acc1[nt] = {0.f, 0.f, 0.f, 0.f};
    #pragma unroll
    for (int k0 = 0; k0 < 128; k0 += 32) {
        s8 a = *reinterpret_cast<const s8*>(Ls + c * LP + k0 + q * 8);
        #pragma unroll
        for (int nt = 0; nt < 8; ++nt) {
            s8 b = *reinterpret_cast<const s8*>(WcT + (nt * 16 + c) * 128 + k0 + q * 8);
            acc1[nt] = __builtin_amdgcn_mfma_f32_16x16x32_bf16(a, b, acc1[nt], 0, 0, 0);
        }
    }

    // ---- residual: + P[row_e] + Q[col_e] ----
    const int rrb = q * 4;
    int er[4], ec[4];
    #pragma unroll
    for (int reg = 0; reg < 4; ++reg) {
        er[reg] = ei[e0w + rrb + reg];
        ec[reg] = ei[NE + e0w + rrb + reg];
    }
    #pragma unroll
    for (int nt = 0; nt < 8; ++nt)
        #pragma unroll
        for (int reg = 0; reg < 4; ++reg)
            acc1[nt][reg] += P[(size_t)er[reg] * 128 + nt * 16 + c]
                           + Q[(size_t)ec[reg] * 128 + nt * 16 + c];

    // ---- LN1 (rows = edges; reduce across 16-lane col groups) ----
    float s[4], ss[4];
    #pragma unroll
    for (int reg = 0; reg < 4; ++reg) { s[reg] = 0.f; ss[reg] = 0.f; }
    #pragma unroll
    for (int nt = 0; nt < 8; ++nt)
        #pragma unroll
        for (int reg = 0; reg < 4; ++reg) {
            float v = acc1[nt][reg];
            s[reg] += v; ss[reg] += v * v;
        }
    #pragma unroll
    for (int m = 1; m < 16; m <<= 1)
        #pragma unroll
        for (int reg = 0; reg < 4; ++reg) {
            s[reg]  += __shfl_xor(s[reg],  m, 64);
            ss[reg] += __shfl_xor(ss[reg], m, 64);
        }
    float mu[4], rs[4];
    #pragma unroll
    for (int reg = 0; reg < 4; ++reg) {
        mu[reg] = s[reg] * (1.f / 128.f);
        float var = ss[reg] * (1.f / 128.f) - mu[reg] * mu[reg];
        rs[reg] = rsqrtf(var + LN_EPS);
    }
    float hv[8][4];
    #pragma unroll
    for (int nt = 0; nt < 8; ++nt) {
        float g = g1[nt * 16 + c], bb = be1[nt * 16 + c];
        #pragma unroll
        for (int reg = 0; reg < 4; ++reg)
            hv[nt][reg] = (acc1[nt][reg] - mu[reg]) * rs[reg] * g + bb;
    }
    // write h (bf16) into LDS A-layout (overwrites ea tile)
    #pragma unroll
    for (int nt = 0; nt < 8; ++nt)
        #pragma unroll
        for (int reg = 0; reg < 4; ++reg)
            Ls[(rrb + reg) * LP + nt * 16 + c] = (short)f2bf(hv[nt][reg]);

    // ---- GEMM2: u = relu(h @ W1 + b1)  (N=256) ----
    f4 acc2[16];
    #pragma unroll
    for (int nt = 0; nt < 16; ++nt) acc2[nt] = {0.f, 0.f, 0.f, 0.f};
    #pragma unroll
    for (int k0 = 0; k0 < 128; k0 += 32) {
        s8 a = *reinterpret_cast<const s8*>(Ls + c * LP + k0 + q * 8);
        #pragma unroll
        for (int nt = 0; nt < 16; ++nt) {
            s8 b = *reinterpret_cast<const s8*>(W1T + (nt * 16 + c) * 128 + k0 + q * 8);
            acc2[nt] = __builtin_amdgcn_mfma_f32_16x16x32_bf16(a, b, acc2[nt], 0, 0, 0);
        }
    }
    #pragma unroll
    for (int nt = 0; nt < 16; ++nt) {
        float bb = b1[nt * 16 + c];
        #pragma unroll
        for (int reg = 0; reg < 4; ++reg) {
            float u = fmaxf(acc2[nt][reg] + bb, 0.f);
            Ls[(rrb + reg) * LP + nt * 16 + c] = (short)f2bf(u);
        }
    }

    // ---- GEMM3: y = h + u @ W2 + b2  (K=256) ----
    f4 acc3[8];
    #pragma unroll
    for (int nt = 0; nt < 8; ++nt) {
        float bb = b2[nt * 16 + c];
        #pragma unroll
        for (int reg = 0; reg < 4; ++reg)
            acc3[nt][reg] = hv[nt][reg] + bb;
    }
    #pragma unroll
    for (int k0 = 0; k0 < 256; k0 += 32) {
        s8 a = *reinterpret_cast<const s8*>(Ls + c * LP + k0 + q * 8);
        #pragma unroll
        for (int nt = 0; nt < 8; ++nt) {
            s8 b = *reinterpret_cast<const s8*>(W2T + (nt * 16 + c) * 256 + k0 + q * 8);
            acc3[nt] = __builtin_amdgcn_mfma_f32_16x16x32_bf16(a, b, acc3[nt], 0, 0, 0);
        }
    }

    // ---- LN2 + store ----
    #pragma unroll
    for (int reg = 0; reg < 4; ++reg) { s[reg] = 0.f; ss[reg] = 0.f; }
    #pragma unroll
    for (int nt = 0; nt < 8; ++nt)
        #pragma unroll
        for (int reg = 0; reg < 4; ++reg) {
            float v = acc3[nt][reg];
            s[reg] += v; ss[reg] += v * v;
        }
    #pragma unroll
    for (int m = 1; m < 16; m <<= 1)
        #pragma unroll
        for (int reg = 0; reg < 4; ++reg) {
            s[reg]  += __shfl_xor(s[reg],  m, 64);
            ss[reg] += __shfl_xor(ss[reg], m, 64);
        }
    #pragma unroll
    for (int reg = 0; reg < 4; ++reg) {
        mu[reg] = s[reg] * (1.f / 128.f);
        float var = ss[reg] * (1.f / 128.f) - mu[reg] * mu[reg];
        rs[reg] = rsqrtf(var + LN_EPS);
    }
    #pragma unroll
    for (int nt = 0; nt < 8; ++nt) {
        float g = g2[nt * 16 + c], bb = be2[nt * 16 + c];
        #pragma unroll
        for (int reg = 0; reg < 4; ++reg) {
            float o = (acc3[nt][reg] - mu[reg]) * rs[reg] * g + bb;
            out[(size_t)(e0w + rrb + reg) * 128 + nt * 16 + c] = o;
        }
    }
}

// ------------------------------------------------------------------ launch ---
extern "C" void kernel_launch(void* const* d_in, const int* in_sizes, int n_in,
                              void* d_out, int out_size, void* d_ws, size_t ws_size,
                              hipStream_t stream) {
    const float* x         = (const float*)d_in[0];
    const int*   ei        = (const int*)  d_in[1];
    const float* edge_attr = (const float*)d_in[2];
    const float* mask      = (const float*)d_in[3];
    const float* W_edge    = (const float*)d_in[5];
    const float* b_edge    = (const float*)d_in[6];
    const float* W1        = (const float*)d_in[7];
    const float* b1        = (const float*)d_in[8];
    const float* W2        = (const float*)d_in[9];
    const float* b2        = (const float*)d_in[10];
    const float* g1        = (const float*)d_in[11];
    const float* be1       = (const float*)d_in[12];
    const float* g2        = (const float*)d_in[13];
    const float* be2       = (const float*)d_in[14];

    float* node_out  = (float*)d_out;                       // [NN, DR]
    float* out_edges = (float*)d_out + (size_t)NN * DR;     // [NE, 128]

    char* ws = (char*)d_ws;
    float*          den = (float*)(ws);                          // 200 KB
    unsigned short* WcT = (unsigned short*)(ws + (256 << 10));   // 32 KB
    unsigned short* W1T = (unsigned short*)(ws + (256 << 10) + 32768);   // 64 KB
    unsigned short* W2T = (unsigned short*)(ws + (256 << 10) + 98304);   // 64 KB
    float*          P   = (float*)(ws + (1 << 20));              // 25.6 MB
    float*          Q   = (float*)(ws + (1 << 20) + 26214400);   // 25.6 MB

    hipMemsetAsync(node_out, 0, (size_t)NN * DR * sizeof(float), stream);
    hipMemsetAsync(den,      0, (size_t)NN * sizeof(float),      stream);

    scatter_kernel<<<(NE * 32) / 256, 256, 0, stream>>>(edge_attr, mask, ei, node_out, den);
    finalize_node_kernel<<<(NN * DR + 255) / 256, 256, 0, stream>>>(x, den, node_out);
    prep_w_kernel<<<320, 256, 0, stream>>>(W_edge, W1, W2, WcT, W1T, W2T);
    pq_kernel<<<(NN + 31) / 32, 256, 0, stream>>>(node_out, W_edge, b_edge, P, Q);
    ffn_kernel<<<NE / 64, 256, 0, stream>>>(edge_attr, ei, P, Q, WcT, W1T, W2T,
                                            b1, b2, g1, be1, g2, be2, out_edges);
}